// Round 2
// baseline (1968.094 us; speedup 1.0000x reference)
//
#include <hip/hip_runtime.h>
#include <math.h>

#define D_MODEL 512
#define NHEAD 8
#define DK 64
#define SEQ 2048
#define NEG_INF -1.0e9f

// ---------------------------------------------------------------------------
// C = A (M x 512) @ W^T  where W is (512 out, 512 in) row-major.
// HEADMAJOR: write C as (B, H, L, DK) head-major (for q/k/v projections).
// else: write C as (M, 512) row-major (for the output projection).
// Tile: BM=128, BN=64, BK=32; 256 threads; 8x4 micro-tile per thread.
// LDS staged TRANSPOSED ([k][m], stride 132/68 floats, 16B-aligned rows):
// inner loop = 2 b128 A-reads (16-lane broadcast) + 1 b128 W-read (2-way,
// free) per 32 FMA -> VALU-bound, not LDS-bound.
// ---------------------------------------------------------------------------
template <bool HEADMAJOR>
__global__ __launch_bounds__(256) void gemm_xwt(const float* __restrict__ A,
                                                const float* __restrict__ W,
                                                float* __restrict__ C) {
  __shared__ __align__(16) float As[32][132];  // [k][m], m = 0..127
  __shared__ __align__(16) float Ws[32][68];   // [k][n], n = 0..63
  const int tid = threadIdx.x;
  const int tx = tid & 15;   // output col group (4 cols)
  const int ty = tid >> 4;   // output row group (8 rows)
  const int mt = blockIdx.x; // 128-row tile
  const int nt = blockIdx.y; // 64-col tile (== head index when HEADMAJOR)

  const float* Ab = A + (size_t)mt * 128 * D_MODEL;
  const float* Wb = W + (size_t)nt * 64 * D_MODEL;

  float acc[8][4] = {};

  for (int k0 = 0; k0 < D_MODEL; k0 += 32) {
    // Stage A tile 128x32 transposed: 1024 float4s, 4 per thread.
#pragma unroll
    for (int v = tid; v < 1024; v += 256) {
      const int r = v >> 3;          // 0..127
      const int kk = (v & 7) << 2;   // 0,4,...,28
      const float4 a = *(const float4*)(Ab + (size_t)r * D_MODEL + k0 + kk);
      As[kk + 0][r] = a.x; As[kk + 1][r] = a.y;
      As[kk + 2][r] = a.z; As[kk + 3][r] = a.w;
    }
    // Stage W tile 64x32 transposed: 512 float4s, 2 per thread.
#pragma unroll
    for (int v = tid; v < 512; v += 256) {
      const int r = v >> 3;          // 0..63
      const int kk = (v & 7) << 2;
      const float4 w = *(const float4*)(Wb + (size_t)r * D_MODEL + k0 + kk);
      Ws[kk + 0][r] = w.x; Ws[kk + 1][r] = w.y;
      Ws[kk + 2][r] = w.z; Ws[kk + 3][r] = w.w;
    }
    __syncthreads();
#pragma unroll
    for (int kk = 0; kk < 32; ++kk) {
      const float4 a0 = *(const float4*)&As[kk][ty << 3];
      const float4 a1 = *(const float4*)&As[kk][(ty << 3) + 4];
      const float4 wv = *(const float4*)&Ws[kk][tx << 2];
      const float a[8] = {a0.x, a0.y, a0.z, a0.w, a1.x, a1.y, a1.z, a1.w};
      const float w[4] = {wv.x, wv.y, wv.z, wv.w};
#pragma unroll
      for (int i = 0; i < 8; ++i)
#pragma unroll
        for (int j = 0; j < 4; ++j) acc[i][j] = fmaf(a[i], w[j], acc[i][j]);
    }
    __syncthreads();
  }

#pragma unroll
  for (int i = 0; i < 8; ++i) {
    const int m = mt * 128 + (ty << 3) + i;
    const float4 o = make_float4(acc[i][0], acc[i][1], acc[i][2], acc[i][3]);
    if (HEADMAJOR) {
      const int b = m >> 11;        // / SEQ
      const int l = m & (SEQ - 1);  // % SEQ
      const int h = nt;             // 64-wide col tile == one head
      const int dk = tx << 2;
      *(float4*)(C + ((((size_t)b * NHEAD + h) * SEQ + l) * DK + dk)) = o;
    } else {
      *(float4*)(C + (size_t)m * D_MODEL + nt * 64 + (tx << 2)) = o;
    }
  }
}

// ---------------------------------------------------------------------------
// Flash attention, fp32. One block per (q-tile of 64 rows, head, batch).
// Q/K staged transposed [d][i]; V row-major [j][d]; P via LDS for the PV GEMM.
// Online softmax with per-row (m, l) kept replicated across the 16 tx threads
// that share a row; reductions via __shfl_xor 1/2/4/8 inside 16-lane groups.
// Mask semantics match jnp.where(mask==0, -1e9, scores): masked score is SET
// to -1e9 (an all-masked prefix self-corrects via alpha=exp(-1e9-m_new)=0).
// ---------------------------------------------------------------------------
__global__ __launch_bounds__(256) void attn_fwd(const float* __restrict__ qh,
                                                const float* __restrict__ kh,
                                                const float* __restrict__ vh,
                                                const int* __restrict__ mask,
                                                float* __restrict__ x) {
  __shared__ __align__(16) float Qs[64][68];  // [d][i]
  __shared__ __align__(16) float Ks[64][68];  // [d][j]
  __shared__ __align__(16) float Vs[64][68];  // [j][d]
  __shared__ __align__(16) float Ps[64][68];  // [i][j]
  __shared__ int Ms[64];

  const int tid = threadIdx.x;
  const int tx = tid & 15;
  const int ty = tid >> 4;
  const int qt = blockIdx.x;  // 0..31
  const int h = blockIdx.y;
  const int b = blockIdx.z;

  const size_t headoff = ((size_t)b * NHEAD + h) * SEQ * DK;
  const float* Qg = qh + headoff + (size_t)qt * 64 * DK;
  const float* Kg = kh + headoff;
  const float* Vg = vh + headoff;

  // Stage Q transposed (reused across all 32 k-tiles).
#pragma unroll
  for (int v = tid; v < 1024; v += 256) {
    const int i = v >> 4;
    const int d4 = (v & 15) << 2;
    const float4 q = *(const float4*)(Qg + (size_t)i * DK + d4);
    Qs[d4 + 0][i] = q.x; Qs[d4 + 1][i] = q.y;
    Qs[d4 + 2][i] = q.z; Qs[d4 + 3][i] = q.w;
  }

  float m_run[4], l_run[4], o[4][4];
#pragma unroll
  for (int i = 0; i < 4; ++i) {
    m_run[i] = -1e30f;
    l_run[i] = 0.f;
#pragma unroll
    for (int j = 0; j < 4; ++j) o[i][j] = 0.f;
  }

  const float scale = 0.125f;  // 1/sqrt(DK)

  for (int kt = 0; kt < 32; ++kt) {
    // Stage K (transposed), V (row-major), mask for this tile.
#pragma unroll
    for (int v = tid; v < 1024; v += 256) {
      const int j = v >> 4;
      const int d4 = (v & 15) << 2;
      const float4 kv = *(const float4*)(Kg + (size_t)(kt * 64 + j) * DK + d4);
      Ks[d4 + 0][j] = kv.x; Ks[d4 + 1][j] = kv.y;
      Ks[d4 + 2][j] = kv.z; Ks[d4 + 3][j] = kv.w;
      const float4 vv = *(const float4*)(Vg + (size_t)(kt * 64 + j) * DK + d4);
      *(float4*)&Vs[j][d4] = vv;
    }
    if (tid < 64) Ms[tid] = mask[b * SEQ + kt * 64 + tid];
    __syncthreads();

    // S = Q @ K^T for this tile (4x4 per thread).
    float s[4][4] = {};
#pragma unroll
    for (int d = 0; d < 64; ++d) {
      const float4 qv = *(const float4*)&Qs[d][ty << 2];
      const float4 kv = *(const float4*)&Ks[d][tx << 2];
      const float qa[4] = {qv.x, qv.y, qv.z, qv.w};
      const float ka[4] = {kv.x, kv.y, kv.z, kv.w};
#pragma unroll
      for (int i = 0; i < 4; ++i)
#pragma unroll
        for (int j = 0; j < 4; ++j) s[i][j] = fmaf(qa[i], ka[j], s[i][j]);
    }

    // Mask + scale.
#pragma unroll
    for (int j = 0; j < 4; ++j) {
      const bool dead = (Ms[(tx << 2) + j] == 0);
#pragma unroll
      for (int i = 0; i < 4; ++i)
        s[i][j] = dead ? NEG_INF : s[i][j] * scale;
    }

    // Online softmax per row; write P to LDS.
#pragma unroll
    for (int i = 0; i < 4; ++i) {
      float rmax = fmaxf(fmaxf(s[i][0], s[i][1]), fmaxf(s[i][2], s[i][3]));
      rmax = fmaxf(rmax, __shfl_xor(rmax, 1));
      rmax = fmaxf(rmax, __shfl_xor(rmax, 2));
      rmax = fmaxf(rmax, __shfl_xor(rmax, 4));
      rmax = fmaxf(rmax, __shfl_xor(rmax, 8));
      const float mnew = fmaxf(m_run[i], rmax);
      const float alpha = __expf(m_run[i] - mnew);
      m_run[i] = mnew;
      float rsum = 0.f;
#pragma unroll
      for (int j = 0; j < 4; ++j) {
        const float p = __expf(s[i][j] - mnew);
        s[i][j] = p;
        rsum += p;
      }
      rsum += __shfl_xor(rsum, 1);
      rsum += __shfl_xor(rsum, 2);
      rsum += __shfl_xor(rsum, 4);
      rsum += __shfl_xor(rsum, 8);
      l_run[i] = l_run[i] * alpha + rsum;
#pragma unroll
      for (int j = 0; j < 4; ++j) {
        o[i][j] *= alpha;
        Ps[(ty << 2) + i][(tx << 2) + j] = s[i][j];
      }
    }
    __syncthreads();

    // O += P @ V, j-blocked by 4: all-float4 LDS reads (V b128 2-way-free,
    // P b128 broadcast), 64 FMA per 8 reads.
#pragma unroll
    for (int j0 = 0; j0 < 64; j0 += 4) {
      float4 vv[4];
#pragma unroll
      for (int t = 0; t < 4; ++t) vv[t] = *(const float4*)&Vs[j0 + t][tx << 2];
#pragma unroll
      for (int i = 0; i < 4; ++i) {
        const float4 p = *(const float4*)&Ps[(ty << 2) + i][j0];
        o[i][0] = fmaf(p.x, vv[0].x, o[i][0]);
        o[i][1] = fmaf(p.x, vv[0].y, o[i][1]);
        o[i][2] = fmaf(p.x, vv[0].z, o[i][2]);
        o[i][3] = fmaf(p.x, vv[0].w, o[i][3]);
        o[i][0] = fmaf(p.y, vv[1].x, o[i][0]);
        o[i][1] = fmaf(p.y, vv[1].y, o[i][1]);
        o[i][2] = fmaf(p.y, vv[1].z, o[i][2]);
        o[i][3] = fmaf(p.y, vv[1].w, o[i][3]);
        o[i][0] = fmaf(p.z, vv[2].x, o[i][0]);
        o[i][1] = fmaf(p.z, vv[2].y, o[i][1]);
        o[i][2] = fmaf(p.z, vv[2].z, o[i][2]);
        o[i][3] = fmaf(p.z, vv[2].w, o[i][3]);
        o[i][0] = fmaf(p.w, vv[3].x, o[i][0]);
        o[i][1] = fmaf(p.w, vv[3].y, o[i][1]);
        o[i][2] = fmaf(p.w, vv[3].z, o[i][2]);
        o[i][3] = fmaf(p.w, vv[3].w, o[i][3]);
      }
    }
    __syncthreads();
  }

  // Finalize: divide by l, write x in (B, L, D_MODEL) row-major.
#pragma unroll
  for (int i = 0; i < 4; ++i) {
    const float inv = 1.0f / l_run[i];
    const int l = qt * 64 + (ty << 2) + i;
    const float4 ov = make_float4(o[i][0] * inv, o[i][1] * inv,
                                  o[i][2] * inv, o[i][3] * inv);
    *(float4*)(x + ((size_t)b * SEQ + l) * D_MODEL + h * DK + (tx << 2)) = ov;
  }
}

// ---------------------------------------------------------------------------
extern "C" void kernel_launch(void* const* d_in, const int* in_sizes, int n_in,
                              void* d_out, int out_size, void* d_ws,
                              size_t ws_size, hipStream_t stream) {
  const float* q = (const float*)d_in[0];
  const float* k = (const float*)d_in[1];
  const float* v = (const float*)d_in[2];
  const int* mask = (const int*)d_in[3];
  const float* w_q = (const float*)d_in[4];
  const float* w_k = (const float*)d_in[5];
  const float* w_v = (const float*)d_in[6];
  const float* w_o = (const float*)d_in[7];
  float* out = (float*)d_out;

  // Workspace layout (floats): qh | kh | vh | x   (16 MB each, 64 MB total)
  float* ws = (float*)d_ws;
  float* qh = ws;
  float* kh = ws + (size_t)4194304;
  float* vh = ws + (size_t)8388608;
  float* xb = ws + (size_t)12582912;

  const int M = 4 * SEQ;  // 8192 rows
  dim3 blk(256);
  dim3 gg(M / 128, D_MODEL / 64);  // 64 x 8

  hipLaunchKernelGGL((gemm_xwt<true>), gg, blk, 0, stream, q, w_q, qh);
  hipLaunchKernelGGL((gemm_xwt<true>), gg, blk, 0, stream, k, w_k, kh);
  hipLaunchKernelGGL((gemm_xwt<true>), gg, blk, 0, stream, v, w_v, vh);

  dim3 ga(SEQ / 64, NHEAD, 4);  // 32 x 8 x 4
  hipLaunchKernelGGL(attn_fwd, ga, blk, 0, stream, qh, kh, vh, mask, xb);

  hipLaunchKernelGGL((gemm_xwt<false>), gg, blk, 0, stream, xb, w_o, out);
}

// Round 3
// 656.082 us; speedup vs baseline: 2.9998x; 2.9998x over previous
//
#include <hip/hip_runtime.h>
#include <math.h>

#define D_MODEL 512
#define NHEAD 8
#define DK 64
#define SEQ 2048
#define NEG_INF -1.0e9f

typedef __attribute__((ext_vector_type(8))) short bf16x8;
typedef __attribute__((ext_vector_type(4))) float f32x4;

// RNE float->bf16 bits, and exact bf16 bits->float.
__device__ inline unsigned short f2bf_bits(float x) {
  union { float f; unsigned u; } v; v.f = x;
  unsigned r = (v.u + 0x7FFFu + ((v.u >> 16) & 1u)) >> 16;
  return (unsigned short)r;
}
__device__ inline float bfbits2f(unsigned short b) {
  union { unsigned u; float f; } v; v.u = ((unsigned)b) << 16;
  return v.f;
}
// Split x ~= hi + lo (both bf16); 3-term MFMA product gives ~fp32 accuracy.
__device__ inline void split2(float x, unsigned short& hi, unsigned short& lo) {
  hi = f2bf_bits(x);
  lo = f2bf_bits(x - bfbits2f(hi));
}

// ---------------------------------------------------------------------------
// fp32 GEMM C = A @ W^T (unchanged from validated round-1 kernel).
// BM=128, BN=64, BK=32; 256 threads; 8x4 micro-tile.
// ---------------------------------------------------------------------------
template <bool HEADMAJOR>
__global__ __launch_bounds__(256) void gemm_xwt(const float* __restrict__ A,
                                                const float* __restrict__ W,
                                                float* __restrict__ C) {
  __shared__ __align__(16) float As[32][132];
  __shared__ __align__(16) float Ws[32][68];
  const int tid = threadIdx.x;
  const int tx = tid & 15;
  const int ty = tid >> 4;
  const int mt = blockIdx.x;
  const int nt = blockIdx.y;

  const float* Ab = A + (size_t)mt * 128 * D_MODEL;
  const float* Wb = W + (size_t)nt * 64 * D_MODEL;

  float acc[8][4] = {};

  for (int k0 = 0; k0 < D_MODEL; k0 += 32) {
#pragma unroll
    for (int v = tid; v < 1024; v += 256) {
      const int r = v >> 3;
      const int kk = (v & 7) << 2;
      const float4 a = *(const float4*)(Ab + (size_t)r * D_MODEL + k0 + kk);
      As[kk + 0][r] = a.x; As[kk + 1][r] = a.y;
      As[kk + 2][r] = a.z; As[kk + 3][r] = a.w;
    }
#pragma unroll
    for (int v = tid; v < 512; v += 256) {
      const int r = v >> 3;
      const int kk = (v & 7) << 2;
      const float4 w = *(const float4*)(Wb + (size_t)r * D_MODEL + k0 + kk);
      Ws[kk + 0][r] = w.x; Ws[kk + 1][r] = w.y;
      Ws[kk + 2][r] = w.z; Ws[kk + 3][r] = w.w;
    }
    __syncthreads();
#pragma unroll
    for (int kk = 0; kk < 32; ++kk) {
      const float4 a0 = *(const float4*)&As[kk][ty << 3];
      const float4 a1 = *(const float4*)&As[kk][(ty << 3) + 4];
      const float4 wv = *(const float4*)&Ws[kk][tx << 2];
      const float a[8] = {a0.x, a0.y, a0.z, a0.w, a1.x, a1.y, a1.z, a1.w};
      const float w[4] = {wv.x, wv.y, wv.z, wv.w};
#pragma unroll
      for (int i = 0; i < 8; ++i)
#pragma unroll
        for (int j = 0; j < 4; ++j) acc[i][j] = fmaf(a[i], w[j], acc[i][j]);
    }
    __syncthreads();
  }

#pragma unroll
  for (int i = 0; i < 8; ++i) {
    const int m = mt * 128 + (ty << 3) + i;
    const float4 o = make_float4(acc[i][0], acc[i][1], acc[i][2], acc[i][3]);
    if (HEADMAJOR) {
      const int b = m >> 11;
      const int l = m & (SEQ - 1);
      const int h = nt;
      const int dk = tx << 2;
      *(float4*)(C + ((((size_t)b * NHEAD + h) * SEQ + l) * DK + dk)) = o;
    } else {
      *(float4*)(C + (size_t)m * D_MODEL + nt * 64 + (tx << 2)) = o;
    }
  }
}

// ---------------------------------------------------------------------------
// Flash attention with split-bf16 MFMA (3-term hi/lo products => ~fp32 acc).
// Block = 256 thr (4 waves), q-tile 64 (16 rows/wave), k-tile 64.
// All LDS tiles XOR-swizzled: elem col ^= (row&7)<<3  (16B-block swizzle)
// -> the 16-lanes-read-16-rows b128 fragment pattern is 2-way (free).
// Fragment layouts (mfma_f32_16x16x32_bf16):
//   A/B: lane holds [row=l&15][k=8*(l>>4)+j], j=0..7 (contiguous 16B)
//   C/D: lane holds [row=4*(l>>4)+reg][col=l&15]    (verified m89)
// V staged transposed (Vt[dv][key]) so PV's B-fragment is contiguous.
// Mask: masked cols set to exactly -1e9 pre-softmax -> exp underflows to 0,
// bitwise-matching reference contribution; all-masked prefixes self-wipe.
// LDS 48.4KB -> 3 blocks/CU.
// ---------------------------------------------------------------------------
__global__ __launch_bounds__(256) void attn_fwd_mfma(
    const float* __restrict__ qh, const float* __restrict__ kh,
    const float* __restrict__ vh, const int* __restrict__ mask,
    float* __restrict__ x) {
  __shared__ unsigned short Ksh_hi[4096], Ksh_lo[4096];
  __shared__ unsigned short Vts_hi[4096], Vts_lo[4096];
  __shared__ unsigned short Ps_hi[4096], Ps_lo[4096];
  __shared__ int Ms[64];

  const int tid = threadIdx.x;
  const int w = tid >> 6, lane = tid & 63, lg = lane >> 4, lc = lane & 15;
  const int qt = blockIdx.x, h = blockIdx.y, b = blockIdx.z;
  const size_t headoff = ((size_t)b * NHEAD + h) * SEQ * DK;
  const float* Qg = qh + headoff + (size_t)qt * 64 * DK;
  const float* Kg = kh + headoff;
  const float* Vg = vh + headoff;

  // Q fragments (A operand), loaded once from global: row w*16+lc, k 8*lg+j.
  bf16x8 qa_hi[2], qa_lo[2];
#pragma unroll
  for (int s = 0; s < 2; ++s) {
    const float* qp = Qg + (size_t)(w * 16 + lc) * DK + s * 32 + lg * 8;
    const float4 a = *(const float4*)qp;
    const float4 c = *(const float4*)(qp + 4);
    const float vals[8] = {a.x, a.y, a.z, a.w, c.x, c.y, c.z, c.w};
#pragma unroll
    for (int j = 0; j < 8; ++j) {
      unsigned short hi, lo;
      split2(vals[j], hi, lo);
      qa_hi[s][j] = (short)hi;
      qa_lo[s][j] = (short)lo;
    }
  }

  float m_run[4] = {-1e30f, -1e30f, -1e30f, -1e30f};
  float l_run[4] = {0.f, 0.f, 0.f, 0.f};
  f32x4 o_acc[4] = {{0, 0, 0, 0}, {0, 0, 0, 0}, {0, 0, 0, 0}, {0, 0, 0, 0}};
  const float scale = 0.125f;  // 1/sqrt(DK)

  for (int kt = 0; kt < 32; ++kt) {
    // ---- stage K (row-major, split, swizzled) ----
#pragma unroll
    for (int p = 0; p < 4; ++p) {
      const int idx = tid + p * 256;
      const int row = idx >> 4, c4 = (idx & 15) << 2;
      const float4 kv = *(const float4*)(Kg + (size_t)(kt * 64 + row) * DK + c4);
      ushort4 hi4, lo4;
      split2(kv.x, hi4.x, lo4.x);
      split2(kv.y, hi4.y, lo4.y);
      split2(kv.z, hi4.z, lo4.z);
      split2(kv.w, hi4.w, lo4.w);
      const int off = row * 64 + (c4 ^ ((row & 7) << 3));
      *(ushort4*)&Ksh_hi[off] = hi4;
      *(ushort4*)&Ksh_lo[off] = lo4;
    }
    // ---- stage V transposed via 4x4 register blocks ----
    {
      const int key0 = (tid >> 4) << 2, dv0 = (tid & 15) << 2;
      const float4 r0 = *(const float4*)(Vg + (size_t)(kt * 64 + key0 + 0) * DK + dv0);
      const float4 r1 = *(const float4*)(Vg + (size_t)(kt * 64 + key0 + 1) * DK + dv0);
      const float4 r2 = *(const float4*)(Vg + (size_t)(kt * 64 + key0 + 2) * DK + dv0);
      const float4 r3 = *(const float4*)(Vg + (size_t)(kt * 64 + key0 + 3) * DK + dv0);
      const float rows[4][4] = {{r0.x, r1.x, r2.x, r3.x},
                                {r0.y, r1.y, r2.y, r3.y},
                                {r0.z, r1.z, r2.z, r3.z},
                                {r0.w, r1.w, r2.w, r3.w}};
#pragma unroll
      for (int t = 0; t < 4; ++t) {
        const int dv = dv0 + t;
        ushort4 hi4, lo4;
        split2(rows[t][0], hi4.x, lo4.x);
        split2(rows[t][1], hi4.y, lo4.y);
        split2(rows[t][2], hi4.z, lo4.z);
        split2(rows[t][3], hi4.w, lo4.w);
        const int off = dv * 64 + (key0 ^ ((dv & 7) << 3));
        *(ushort4*)&Vts_hi[off] = hi4;
        *(ushort4*)&Vts_lo[off] = lo4;
      }
    }
    if (tid < 64) Ms[tid] = mask[b * SEQ + kt * 64 + tid];
    __syncthreads();

    // ---- QK^T: wave computes S[16 q x 64 k] as 4 col-tiles ----
    f32x4 s_acc[4];
#pragma unroll
    for (int ct = 0; ct < 4; ++ct) {
      f32x4 acc = {0, 0, 0, 0};
#pragma unroll
      for (int s = 0; s < 2; ++s) {
        const int row = ct * 16 + lc;
        const int off = row * 64 + ((s * 32 + lg * 8) ^ ((row & 7) << 3));
        const bf16x8 kb_hi = *(const bf16x8*)&Ksh_hi[off];
        const bf16x8 kb_lo = *(const bf16x8*)&Ksh_lo[off];
        acc = __builtin_amdgcn_mfma_f32_16x16x32_bf16(qa_hi[s], kb_hi, acc, 0, 0, 0);
        acc = __builtin_amdgcn_mfma_f32_16x16x32_bf16(qa_hi[s], kb_lo, acc, 0, 0, 0);
        acc = __builtin_amdgcn_mfma_f32_16x16x32_bf16(qa_lo[s], kb_hi, acc, 0, 0, 0);
      }
      s_acc[ct] = acc;
    }

    // ---- mask + scale + online softmax (rows = 4*lg+reg, replicated x16) --
    float p_val[4][4];  // [ct][reg]
    int mv[4];
#pragma unroll
    for (int ct = 0; ct < 4; ++ct) mv[ct] = Ms[ct * 16 + lc];
#pragma unroll
    for (int reg = 0; reg < 4; ++reg) {
      const float s0 = mv[0] ? s_acc[0][reg] * scale : NEG_INF;
      const float s1 = mv[1] ? s_acc[1][reg] * scale : NEG_INF;
      const float s2 = mv[2] ? s_acc[2][reg] * scale : NEG_INF;
      const float s3 = mv[3] ? s_acc[3][reg] * scale : NEG_INF;
      float rmax = fmaxf(fmaxf(s0, s1), fmaxf(s2, s3));
      rmax = fmaxf(rmax, __shfl_xor(rmax, 1));
      rmax = fmaxf(rmax, __shfl_xor(rmax, 2));
      rmax = fmaxf(rmax, __shfl_xor(rmax, 4));
      rmax = fmaxf(rmax, __shfl_xor(rmax, 8));
      const float mnew = fmaxf(m_run[reg], rmax);
      const float alpha = __expf(m_run[reg] - mnew);
      m_run[reg] = mnew;
      const float p0 = __expf(s0 - mnew), p1 = __expf(s1 - mnew);
      const float p2 = __expf(s2 - mnew), p3 = __expf(s3 - mnew);
      float rsum = p0 + p1 + p2 + p3;
      rsum += __shfl_xor(rsum, 1);
      rsum += __shfl_xor(rsum, 2);
      rsum += __shfl_xor(rsum, 4);
      rsum += __shfl_xor(rsum, 8);
      l_run[reg] = l_run[reg] * alpha + rsum;
      p_val[0][reg] = p0; p_val[1][reg] = p1;
      p_val[2][reg] = p2; p_val[3][reg] = p3;
#pragma unroll
      for (int dt = 0; dt < 4; ++dt) o_acc[dt][reg] *= alpha;
    }

    // ---- write P (split) to wave-private LDS rows ----
#pragma unroll
    for (int ct = 0; ct < 4; ++ct)
#pragma unroll
      for (int reg = 0; reg < 4; ++reg) {
        const int row = w * 16 + lg * 4 + reg;
        const int col = ct * 16 + lc;
        unsigned short hi, lo;
        split2(p_val[ct][reg], hi, lo);
        const int off = row * 64 + (col ^ ((row & 7) << 3));
        Ps_hi[off] = hi;
        Ps_lo[off] = lo;
      }

    // ---- PV: O[16 q x 64 d] += P @ V ----
#pragma unroll
    for (int s = 0; s < 2; ++s) {
      const int arow = w * 16 + lc;
      const int aoff = arow * 64 + ((s * 32 + lg * 8) ^ ((arow & 7) << 3));
      const bf16x8 pa_hi = *(const bf16x8*)&Ps_hi[aoff];
      const bf16x8 pa_lo = *(const bf16x8*)&Ps_lo[aoff];
#pragma unroll
      for (int dt = 0; dt < 4; ++dt) {
        const int brow = dt * 16 + lc;
        const int boff = brow * 64 + ((s * 32 + lg * 8) ^ ((brow & 7) << 3));
        const bf16x8 vb_hi = *(const bf16x8*)&Vts_hi[boff];
        const bf16x8 vb_lo = *(const bf16x8*)&Vts_lo[boff];
        o_acc[dt] = __builtin_amdgcn_mfma_f32_16x16x32_bf16(pa_hi, vb_hi, o_acc[dt], 0, 0, 0);
        o_acc[dt] = __builtin_amdgcn_mfma_f32_16x16x32_bf16(pa_hi, vb_lo, o_acc[dt], 0, 0, 0);
        o_acc[dt] = __builtin_amdgcn_mfma_f32_16x16x32_bf16(pa_lo, vb_hi, o_acc[dt], 0, 0, 0);
      }
    }
    __syncthreads();
  }

  // ---- finalize: /l, write x (B, L, D_MODEL) ----
#pragma unroll
  for (int reg = 0; reg < 4; ++reg) {
    const float inv = 1.0f / l_run[reg];
    const int row = w * 16 + lg * 4 + reg;
    const size_t base = ((size_t)b * SEQ + qt * 64 + row) * D_MODEL + h * DK;
#pragma unroll
    for (int dt = 0; dt < 4; ++dt)
      x[base + dt * 16 + lc] = o_acc[dt][reg] * inv;
  }
}

// ---------------------------------------------------------------------------
extern "C" void kernel_launch(void* const* d_in, const int* in_sizes, int n_in,
                              void* d_out, int out_size, void* d_ws,
                              size_t ws_size, hipStream_t stream) {
  const float* q = (const float*)d_in[0];
  const float* k = (const float*)d_in[1];
  const float* v = (const float*)d_in[2];
  const int* mask = (const int*)d_in[3];
  const float* w_q = (const float*)d_in[4];
  const float* w_k = (const float*)d_in[5];
  const float* w_v = (const float*)d_in[6];
  const float* w_o = (const float*)d_in[7];
  float* out = (float*)d_out;

  float* ws = (float*)d_ws;
  float* qh = ws;
  float* kh = ws + (size_t)4194304;
  float* vh = ws + (size_t)8388608;
  float* xb = ws + (size_t)12582912;

  const int M = 4 * SEQ;
  dim3 blk(256);
  dim3 gg(M / 128, D_MODEL / 64);

  hipLaunchKernelGGL((gemm_xwt<true>), gg, blk, 0, stream, q, w_q, qh);
  hipLaunchKernelGGL((gemm_xwt<true>), gg, blk, 0, stream, k, w_k, kh);
  hipLaunchKernelGGL((gemm_xwt<true>), gg, blk, 0, stream, v, w_v, vh);

  dim3 ga(SEQ / 64, NHEAD, 4);
  hipLaunchKernelGGL(attn_fwd_mfma, ga, blk, 0, stream, qh, kh, vh, mask, xb);

  hipLaunchKernelGGL((gemm_xwt<false>), gg, blk, 0, stream, xb, w_o, out);
}

// Round 4
// 379.214 us; speedup vs baseline: 5.1899x; 1.7301x over previous
//
#include <hip/hip_runtime.h>

#define D_MODEL 512
#define NHEAD 8
#define DK 64
#define SEQ 2048
#define NEG_INF -1.0e9f

typedef __attribute__((ext_vector_type(8))) short bf16x8;
typedef __attribute__((ext_vector_type(4))) float f32x4;

// ---- bf16 split helpers -----------------------------------------------------
// RNE float->bf16 bits (validated round 2/3).
__device__ __forceinline__ unsigned short f2bf_rne(float x) {
  union { float f; unsigned u; } v; v.f = x;
  return (unsigned short)((v.u + 0x7FFFu + ((v.u >> 16) & 1u)) >> 16);
}
__device__ __forceinline__ float bf2f(unsigned short b) {
  union { unsigned u; float f; } v; v.u = ((unsigned)b) << 16;
  return v.f;
}
// x ~= hi + lo + eps, eps ~ 2^-17|x|; used off the hot path.
__device__ __forceinline__ void split_rne(float x, unsigned short& hi,
                                          unsigned short& lo) {
  hi = f2bf_rne(x);
  lo = f2bf_rne(x - bf2f(hi));
}
// Cheap 4-op truncating split: eps ~ 2^-14|x| (fp32-class after 3-term MFMA).
__device__ __forceinline__ void split_trunc(float x, unsigned short& hi,
                                            unsigned short& lo) {
  union { float f; unsigned u; } v; v.f = x;
  hi = (unsigned short)(v.u >> 16);
  union { float f; unsigned u; } r; r.f = x - bf2f(hi);
  lo = (unsigned short)(r.u >> 16);
}

// Async global->LDS, 16B per lane; dest = wave-uniform base + lane*16.
__device__ __forceinline__ void gload_lds16(const void* g, void* l) {
  __builtin_amdgcn_global_load_lds(
      (const __attribute__((address_space(1))) unsigned int*)g,
      (__attribute__((address_space(3))) unsigned int*)l, 16, 0, 0);
}

// ---------------------------------------------------------------------------
// Pass 0: split fp32 matrix (Mx512, M=8192) into bf16 hi/lo, stored in
// GEMM-ready tiled+swizzled layout: tile (mt=m/64, kt=c/64) contiguous 4096
// ushorts; within tile off = r*64 + (cc ^ 8*(r&7)). Memory-bound.
// ---------------------------------------------------------------------------
__global__ __launch_bounds__(256) void split_tile(const float* __restrict__ A,
                                                  unsigned short* __restrict__ Xh,
                                                  unsigned short* __restrict__ Xl) {
  const int e = blockIdx.x * 256 + threadIdx.x;  // float4 index
  const int m = e >> 7;
  const int c0 = (e & 127) << 2;
  const float4 a = *(const float4*)(A + (size_t)m * 512 + c0);
  ushort4 h4, l4;
  split_rne(a.x, h4.x, l4.x);
  split_rne(a.y, h4.y, l4.y);
  split_rne(a.z, h4.z, l4.z);
  split_rne(a.w, h4.w, l4.w);
  const int r = m & 63, mt = m >> 6, kt = c0 >> 6, cc = c0 & 63;
  const int off = (mt * 8 + kt) * 4096 + r * 64 + (cc ^ ((r & 7) << 3));
  *(ushort4*)&Xh[off] = h4;
  *(ushort4*)&Xl[off] = l4;
}

// ---------------------------------------------------------------------------
// Split-bf16 MFMA GEMM: C = A @ W^T.  A: pre-split tiled hi/lo (8192x512).
// W: fp32 (512 out x 512 in), split in-kernel (trunc). 3-term products.
// Block 256 = 4 waves; tile BM=64 (16 rows/wave), BN=64, BK=64, 8 k-steps.
// Epilogue variants write attn-ready layouts.
// ---------------------------------------------------------------------------
#define EPI_Q 0
#define EPI_K 1
#define EPI_VT 2
#define EPI_OUT 3

template <int EPI>
__global__ __launch_bounds__(256) void gemm_split(
    const unsigned short* __restrict__ Ah, const unsigned short* __restrict__ Al,
    const float* __restrict__ W,
    unsigned short* __restrict__ Ch, unsigned short* __restrict__ Cl,
    float* __restrict__ Cf) {
  __shared__ unsigned short Ash[4096], Asl[4096], Wsh[4096], Wsl[4096];
  const int tid = threadIdx.x;
  const int w = tid >> 6, lane = tid & 63, lg = lane >> 4, lc = lane & 15;
  const int mt = blockIdx.x, nt = blockIdx.y;

  f32x4 acc[4] = {{0, 0, 0, 0}, {0, 0, 0, 0}, {0, 0, 0, 0}, {0, 0, 0, 0}};

  const int wr = tid >> 2;         // W stage: row 0..63
  const int wc0 = (tid & 3) << 4;  // W stage: col base 0/16/32/48
  const float* Wrow = W + (size_t)(nt * 64 + wr) * 512;

  for (int kt = 0; kt < 8; ++kt) {
    // A: direct global->LDS (layout already split+swizzled+tiled).
    const size_t tb = (size_t)(mt * 8 + kt) * 4096;
    const unsigned short* sh = Ah + tb + w * 512 + lane * 8;
    const unsigned short* sl = Al + tb + w * 512 + lane * 8;
    gload_lds16(sh, &Ash[w * 512]);
    gload_lds16(sh + 2048, &Ash[w * 512 + 2048]);
    gload_lds16(sl, &Asl[w * 512]);
    gload_lds16(sl + 2048, &Asl[w * 512 + 2048]);
    // W: fp32 load + trunc split + swizzled LDS write.
#pragma unroll
    for (int j = 0; j < 4; ++j) {
      const float4 wv = *(const float4*)(Wrow + kt * 64 + wc0 + j * 4);
      ushort4 h4, l4;
      split_trunc(wv.x, h4.x, l4.x);
      split_trunc(wv.y, h4.y, l4.y);
      split_trunc(wv.z, h4.z, l4.z);
      split_trunc(wv.w, h4.w, l4.w);
      const int off = wr * 64 + ((wc0 + j * 4) ^ ((wr & 7) << 3));
      *(ushort4*)&Wsh[off] = h4;
      *(ushort4*)&Wsl[off] = l4;
    }
    __syncthreads();
#pragma unroll
    for (int s = 0; s < 2; ++s) {
      const int arow = w * 16 + lc;
      const int aoff = arow * 64 + ((s * 32 + lg * 8) ^ ((arow & 7) << 3));
      const bf16x8 a_hi = *(const bf16x8*)&Ash[aoff];
      const bf16x8 a_lo = *(const bf16x8*)&Asl[aoff];
#pragma unroll
      for (int ct = 0; ct < 4; ++ct) {
        const int brow = ct * 16 + lc;
        const int boff = brow * 64 + ((s * 32 + lg * 8) ^ ((brow & 7) << 3));
        const bf16x8 b_hi = *(const bf16x8*)&Wsh[boff];
        const bf16x8 b_lo = *(const bf16x8*)&Wsl[boff];
        acc[ct] = __builtin_amdgcn_mfma_f32_16x16x32_bf16(a_hi, b_hi, acc[ct], 0, 0, 0);
        acc[ct] = __builtin_amdgcn_mfma_f32_16x16x32_bf16(a_hi, b_lo, acc[ct], 0, 0, 0);
        acc[ct] = __builtin_amdgcn_mfma_f32_16x16x32_bf16(a_lo, b_hi, acc[ct], 0, 0, 0);
      }
    }
    __syncthreads();
  }

  // Epilogue. C/D layout: lane holds row = 4*lg + reg, col = lc (within each
  // 16-col tile ct). Global row m -> (b, l).
#pragma unroll
  for (int ct = 0; ct < 4; ++ct) {
#pragma unroll
    for (int reg = 0; reg < 4; ++reg) {
      const float val = acc[ct][reg];
      const int row = w * 16 + lg * 4 + reg;
      const int m = mt * 64 + row;
      const int col = ct * 16 + lc;
      if (EPI == EPI_OUT) {
        Cf[(size_t)m * 512 + nt * 64 + col] = val;
      } else {
        unsigned short hi, lo;
        split_rne(val, hi, lo);
        const int b = m >> 11, l = m & 2047;
        if (EPI == EPI_Q) {
          // row-major [b][h][l][dk]
          const size_t o = ((size_t)(b * 8 + nt) * 2048 + l) * 64 + col;
          Ch[o] = hi; Cl[o] = lo;
        } else if (EPI == EPI_K) {
          // K tiles: [b][h][kt][key r][dk c^swz]
          const int kti = l >> 6, r = l & 63;
          const size_t o = ((size_t)((b * 8 + nt) * 32 + kti)) * 4096 +
                           r * 64 + (col ^ ((r & 7) << 3));
          Ch[o] = hi; Cl[o] = lo;
        } else {
          // V^T tiles: [b][h][kt][dv=col][key^swz]
          const int kti = l >> 6, key = l & 63;
          const size_t o = ((size_t)((b * 8 + nt) * 32 + kti)) * 4096 +
                           col * 64 + (key ^ ((col & 7) << 3));
          Ch[o] = hi; Cl[o] = lo;
        }
      }
    }
  }
}

// ---------------------------------------------------------------------------
// Flash attention, split-bf16 MFMA. All staging is pure global_load_lds of
// pre-split pre-swizzled tiles (zero conversion VALU in the k-loop).
// Epilogue writes x as split+tiled hi/lo for the out-projection GEMM.
// ---------------------------------------------------------------------------
__global__ __launch_bounds__(256) void attn_fwd_mfma(
    const unsigned short* __restrict__ qhh, const unsigned short* __restrict__ qhl,
    const unsigned short* __restrict__ khh, const unsigned short* __restrict__ khl,
    const unsigned short* __restrict__ vth, const unsigned short* __restrict__ vtl,
    const int* __restrict__ mask,
    unsigned short* __restrict__ xh, unsigned short* __restrict__ xl) {
  __shared__ unsigned short Ksh_h[4096], Ksh_l[4096];
  __shared__ unsigned short Vts_h[4096], Vts_l[4096];
  __shared__ unsigned short Ps_h[4096], Ps_l[4096];
  __shared__ int Ms[64];

  const int tid = threadIdx.x;
  const int w = tid >> 6, lane = tid & 63, lg = lane >> 4, lc = lane & 15;
  const int qt = blockIdx.x, h = blockIdx.y, b = blockIdx.z;

  // Q fragments straight from global (bf16x8 = 16B loads), once per block.
  const size_t qbase = ((size_t)(b * 8 + h) * 2048 + qt * 64 + w * 16 + lc) * 64;
  bf16x8 qa_hi[2], qa_lo[2];
#pragma unroll
  for (int s = 0; s < 2; ++s) {
    qa_hi[s] = *(const bf16x8*)(qhh + qbase + s * 32 + lg * 8);
    qa_lo[s] = *(const bf16x8*)(qhl + qbase + s * 32 + lg * 8);
  }

  float m_run[4] = {-1e30f, -1e30f, -1e30f, -1e30f};
  float l_run[4] = {0.f, 0.f, 0.f, 0.f};
  f32x4 o_acc[4] = {{0, 0, 0, 0}, {0, 0, 0, 0}, {0, 0, 0, 0}, {0, 0, 0, 0}};
  const float scale = 0.125f;  // 1/sqrt(DK)

  for (int kt = 0; kt < 32; ++kt) {
    // ---- stage K/Vt tiles: 8 async 16B/lane copies, zero VALU ----
    const size_t tb = ((size_t)((b * 8 + h) * 32 + kt)) * 4096;
    const int so = w * 512 + lane * 8;
    gload_lds16(khh + tb + so, &Ksh_h[w * 512]);
    gload_lds16(khh + tb + so + 2048, &Ksh_h[w * 512 + 2048]);
    gload_lds16(khl + tb + so, &Ksh_l[w * 512]);
    gload_lds16(khl + tb + so + 2048, &Ksh_l[w * 512 + 2048]);
    gload_lds16(vth + tb + so, &Vts_h[w * 512]);
    gload_lds16(vth + tb + so + 2048, &Vts_h[w * 512 + 2048]);
    gload_lds16(vtl + tb + so, &Vts_l[w * 512]);
    gload_lds16(vtl + tb + so + 2048, &Vts_l[w * 512 + 2048]);
    if (tid < 64) Ms[tid] = mask[b * SEQ + kt * 64 + tid];
    __syncthreads();

    // ---- QK^T: wave computes S[16 q x 64 k] as 4 col-tiles ----
    f32x4 s_acc[4];
#pragma unroll
    for (int ct = 0; ct < 4; ++ct) {
      f32x4 acc = {0, 0, 0, 0};
#pragma unroll
      for (int s = 0; s < 2; ++s) {
        const int row = ct * 16 + lc;
        const int off = row * 64 + ((s * 32 + lg * 8) ^ ((row & 7) << 3));
        const bf16x8 kb_hi = *(const bf16x8*)&Ksh_h[off];
        const bf16x8 kb_lo = *(const bf16x8*)&Ksh_l[off];
        acc = __builtin_amdgcn_mfma_f32_16x16x32_bf16(qa_hi[s], kb_hi, acc, 0, 0, 0);
        acc = __builtin_amdgcn_mfma_f32_16x16x32_bf16(qa_hi[s], kb_lo, acc, 0, 0, 0);
        acc = __builtin_amdgcn_mfma_f32_16x16x32_bf16(qa_lo[s], kb_hi, acc, 0, 0, 0);
      }
      s_acc[ct] = acc;
    }

    // ---- mask + scale + online softmax ----
    float p_val[4][4];
    int mv[4];
#pragma unroll
    for (int ct = 0; ct < 4; ++ct) mv[ct] = Ms[ct * 16 + lc];
#pragma unroll
    for (int reg = 0; reg < 4; ++reg) {
      const float s0 = mv[0] ? s_acc[0][reg] * scale : NEG_INF;
      const float s1 = mv[1] ? s_acc[1][reg] * scale : NEG_INF;
      const float s2 = mv[2] ? s_acc[2][reg] * scale : NEG_INF;
      const float s3 = mv[3] ? s_acc[3][reg] * scale : NEG_INF;
      float rmax = fmaxf(fmaxf(s0, s1), fmaxf(s2, s3));
      rmax = fmaxf(rmax, __shfl_xor(rmax, 1));
      rmax = fmaxf(rmax, __shfl_xor(rmax, 2));
      rmax = fmaxf(rmax, __shfl_xor(rmax, 4));
      rmax = fmaxf(rmax, __shfl_xor(rmax, 8));
      const float mnew = fmaxf(m_run[reg], rmax);
      const float alpha = __expf(m_run[reg] - mnew);
      m_run[reg] = mnew;
      const float p0 = __expf(s0 - mnew), p1 = __expf(s1 - mnew);
      const float p2 = __expf(s2 - mnew), p3 = __expf(s3 - mnew);
      float rsum = p0 + p1 + p2 + p3;
      rsum += __shfl_xor(rsum, 1);
      rsum += __shfl_xor(rsum, 2);
      rsum += __shfl_xor(rsum, 4);
      rsum += __shfl_xor(rsum, 8);
      l_run[reg] = l_run[reg] * alpha + rsum;
      p_val[0][reg] = p0; p_val[1][reg] = p1;
      p_val[2][reg] = p2; p_val[3][reg] = p3;
#pragma unroll
      for (int dt = 0; dt < 4; ++dt) o_acc[dt][reg] *= alpha;
    }

    // ---- write P (cheap trunc split) to wave-private LDS rows ----
#pragma unroll
    for (int ct = 0; ct < 4; ++ct)
#pragma unroll
      for (int reg = 0; reg < 4; ++reg) {
        const int row = w * 16 + lg * 4 + reg;
        const int col = ct * 16 + lc;
        unsigned short hi, lo;
        split_trunc(p_val[ct][reg], hi, lo);
        const int off = row * 64 + (col ^ ((row & 7) << 3));
        Ps_h[off] = hi;
        Ps_l[off] = lo;
      }

    // ---- PV: O[16 q x 64 d] += P @ V ----
#pragma unroll
    for (int s = 0; s < 2; ++s) {
      const int arow = w * 16 + lc;
      const int aoff = arow * 64 + ((s * 32 + lg * 8) ^ ((arow & 7) << 3));
      const bf16x8 pa_hi = *(const bf16x8*)&Ps_h[aoff];
      const bf16x8 pa_lo = *(const bf16x8*)&Ps_l[aoff];
#pragma unroll
      for (int dt = 0; dt < 4; ++dt) {
        const int brow = dt * 16 + lc;
        const int boff = brow * 64 + ((s * 32 + lg * 8) ^ ((brow & 7) << 3));
        const bf16x8 vb_hi = *(const bf16x8*)&Vts_h[boff];
        const bf16x8 vb_lo = *(const bf16x8*)&Vts_l[boff];
        o_acc[dt] = __builtin_amdgcn_mfma_f32_16x16x32_bf16(pa_hi, vb_hi, o_acc[dt], 0, 0, 0);
        o_acc[dt] = __builtin_amdgcn_mfma_f32_16x16x32_bf16(pa_hi, vb_lo, o_acc[dt], 0, 0, 0);
        o_acc[dt] = __builtin_amdgcn_mfma_f32_16x16x32_bf16(pa_lo, vb_hi, o_acc[dt], 0, 0, 0);
      }
    }
    __syncthreads();
  }

  // ---- finalize: /l, split, write x tiles for the out-proj GEMM ----
#pragma unroll
  for (int reg = 0; reg < 4; ++reg) {
    const float inv = 1.0f / l_run[reg];
    const int row = w * 16 + lg * 4 + reg;
    const size_t tbase = ((size_t)((b * 32 + qt) * 8 + h)) * 4096;
#pragma unroll
    for (int dt = 0; dt < 4; ++dt) {
      const int c = dt * 16 + lc;
      unsigned short hi, lo;
      split_rne(o_acc[dt][reg] * inv, hi, lo);
      const size_t o = tbase + row * 64 + (c ^ ((row & 7) << 3));
      xh[o] = hi;
      xl[o] = lo;
    }
  }
}

// ---------------------------------------------------------------------------
extern "C" void kernel_launch(void* const* d_in, const int* in_sizes, int n_in,
                              void* d_out, int out_size, void* d_ws,
                              size_t ws_size, hipStream_t stream) {
  const float* q = (const float*)d_in[0];
  const float* k = (const float*)d_in[1];
  const float* v = (const float*)d_in[2];
  const int* mask = (const int*)d_in[3];
  const float* w_q = (const float*)d_in[4];
  const float* w_k = (const float*)d_in[5];
  const float* w_v = (const float*)d_in[6];
  const float* w_o = (const float*)d_in[7];
  float* out = (float*)d_out;

  // ws: 8 x 4,194,304 ushorts = 64 MB. X region doubles as (pre-split A
  // staging for projections) then (x_hi/x_lo between attn and out-proj).
  unsigned short* ws = (unsigned short*)d_ws;
  const size_t SZ = 4194304;
  unsigned short* Xh = ws;
  unsigned short* Xl = ws + SZ;
  unsigned short* qh_h = ws + 2 * SZ; unsigned short* qh_l = ws + 3 * SZ;
  unsigned short* kh_h = ws + 4 * SZ; unsigned short* kh_l = ws + 5 * SZ;
  unsigned short* vt_h = ws + 6 * SZ; unsigned short* vt_l = ws + 7 * SZ;

  dim3 blk(256);
  dim3 gs(4096);      // split passes
  dim3 gg(128, 8);    // GEMMs
  dim3 ga(32, 8, 4);  // attention

  split_tile<<<gs, blk, 0, stream>>>(q, Xh, Xl);
  gemm_split<EPI_Q><<<gg, blk, 0, stream>>>(Xh, Xl, w_q, qh_h, qh_l, nullptr);
  split_tile<<<gs, blk, 0, stream>>>(k, Xh, Xl);
  gemm_split<EPI_K><<<gg, blk, 0, stream>>>(Xh, Xl, w_k, kh_h, kh_l, nullptr);
  split_tile<<<gs, blk, 0, stream>>>(v, Xh, Xl);
  gemm_split<EPI_VT><<<gg, blk, 0, stream>>>(Xh, Xl, w_v, vt_h, vt_l, nullptr);
  attn_fwd_mfma<<<ga, blk, 0, stream>>>(qh_h, qh_l, kh_h, kh_l, vt_h, vt_l,
                                        mask, Xh, Xl);
  gemm_split<EPI_OUT><<<gg, blk, 0, stream>>>(Xh, Xl, w_o, nullptr, nullptr, out);
}